// Round 8
// baseline (36.248 us; speedup 1.0000x reference)
//
#include <hip/hip_runtime.h>

// ---------------- problem constants ----------------
#define NC    2
#define NB    9
#define NNODE 820
#define NL    3
#define NK    17
#define G     4          // nodes per block
#define NGB   205        // 820 / G

#define EPSF     1e-30f
// scale constant: C = sqrt(log2(e)/2); exp(-d^2/2) == exp2(-(d*C)^2)
#define C_SCF    0.84932178f
// ISQ2PI / C   (pdf normalization when one 1/sigma factor is C-scaled)
#define KLPN     0.46971920f
// I2PI / C^2   (normalization when two 1/sigma factors are C-scaled)
#define KE       0.22063560f

// output layout (flat f32 offsets, concatenated in reference return order)
#define OFF_XN    0LL
#define OFF_XE    752760LL
#define OFF_LPN   26315388LL
#define OFF_LPE   27068148LL
#define OFF_ALPHA 39849462LL
#define OFF_O1    39849516LL
#define OFF_O2    39893742LL

// ---------------- compile-time Gauss-Hermite nodes (n=17) ----------------
constexpr double csqrt(double v) {
    if (v <= 0.0) return 0.0;
    double y = v > 1.0 ? v : 1.0;
    for (int i = 0; i < 80; ++i) y = 0.5 * (y + v / y);
    return y;
}

struct HNodesF { float x[NK]; };

constexpr HNodesF compute_nodes() {
    const int n = NK;
    const double PIM4 = 0.7511255444649425;   // pi^{-1/4}
    double c1[NK + 1] = {}, c2[NK + 1] = {};
    for (int j = 1; j <= n; ++j) {
        c1[j] = csqrt(2.0 / (double)j);
        c2[j] = csqrt(((double)j - 1.0) / (double)j);
    }
    const double PPC = csqrt(2.0 * (double)n);
    double xr[9] = {};
    double z = 0.0;
    for (int i = 0; i < 9; ++i) {
        if (i == 0)      z = csqrt(2.0 * n + 1.0) - 1.85575 * 0.552905;   // 35^-0.16667
        else if (i == 1) z -= 1.14 * 3.34327 / z;                          // 17^0.426
        else if (i == 2) z = 1.86 * z - 0.86 * xr[0];
        else if (i == 3) z = 1.91 * z - 0.91 * xr[1];
        else             z = 2.0 * z - xr[i - 2];
        for (int it = 0; it < 24; ++it) {
            double p1 = PIM4, p2 = 0.0;
            for (int j = 1; j <= n; ++j) {
                double p3 = p2;
                p2 = p1;
                p1 = z * c1[j] * p2 - c2[j] * p3;
            }
            double pp = PPC * p2;
            double z1 = z;
            z = z1 - p1 / pp;
            double d = z - z1; if (d < 0.0) d = -d;
            if (d <= 3.0e-14) break;
        }
        xr[i] = z;
    }
    HNodesF f{};
    for (int i = 0; i < 9; ++i) {
        f.x[16 - i] = (float)xr[i];
        f.x[i]      = (float)(-xr[i]);
    }
    return f;
}

// (xi*sqrt2, xj*sqrt2) table for q in [0,289): xi = x[q%17], xj = x[q/17]
struct TabF { float v[289 * 2]; };
constexpr TabF make_tab() {
    HNodesF h = compute_nodes();
    TabF t{};
    for (int q = 0; q < 289; ++q) {
        t.v[2 * q]     = (float)((double)h.x[q % 17] * 1.4142135623730951);
        t.v[2 * q + 1] = (float)((double)h.x[q / 17] * 1.4142135623730951);
    }
    return t;
}
constexpr TabF TABC = make_tab();

__device__ __forceinline__ int idOf(int n) {
    if (n < 729) { return 729 + (n / 81) * 9 + (n % 27) / 3; }
    if (n < 810) { int m = n - 729; return 810 + (m / 27) * 3 + (m % 9) / 3; }
    return 819;
}

__device__ __forceinline__ float rcpf(float x) { return __builtin_amdgcn_rcpf(x); }

__device__ __forceinline__ float sel3(float a0, float a1, float a2, int i) {
    float r = a0;
    r = (i == 1) ? a1 : r;
    r = (i == 2) ? a2 : r;
    return r;
}

// copy `count` floats LDS -> global with aligned float4 body + scalar head/tail
__device__ __forceinline__ void store_aligned(float* __restrict__ gdst,
                                              const float* __restrict__ lsrc,
                                              int count, int tid) {
    int mis  = (int)((((uintptr_t)gdst) >> 2) & 3);   // misalignment in floats
    int head = (4 - mis) & 3;
    if (head > count) head = count;
    if (tid < head) gdst[tid] = lsrc[tid];
    int rem   = count - head;
    int quads = rem >> 2;
    const float* ls = lsrc + head;
    float* gs = gdst + head;
    for (int f = tid; f < quads; f += 256) {
        float4 v = *(const float4*)(ls + 4 * f);      // ds_read_b128
        *(float4*)(gs + 4 * f) = v;                   // global_store_dwordx4, aligned
    }
    int tail = rem & 3;
    if (tid < tail) gs[(quads << 2) + tid] = ls[(quads << 2) + tid];
}

// ---------------- single fused kernel ----------------
// grid = (205, 18); block (g, cb) handles nodes n0..n0+3 of batch-slice cb.
// Factorized mixture (R7) + LDS-staged, 16B-aligned dwordx4 write-out (R8):
// the bulk streams (xe 102MB, lpe 51MB) were 8B/4B-per-lane stores at odd
// row offsets — caps effective HBM write BW at ~4.8 TB/s. Staging each
// node's contiguous xe (1734 f) / lpe (867 f) rows in LDS and streaming
// them out as aligned float4 matches the fill-kernel store pattern.
__global__ __launch_bounds__(256) void fused_kernel(const float* __restrict__ mu,
                                                    const float* __restrict__ sg,
                                                    const float* __restrict__ w,
                                                    float* __restrict__ out) {
    const int g   = blockIdx.x;           // 0..204
    const int cb  = blockIdx.y;           // 0..17
    const int b   = cb % NB;
    const int n0  = g * G;
    const int tid = threadIdx.x;

    __shared__ float2 tab[289];
    __shared__ float  params[48];         // [nn][12]: mu1[3],sg1[3],mu2[3],sg2[3]
    __shared__ float  sCEj[612];          // [sec][m][j]  sec=nn*3+l1
    __shared__ float  sEi [612];          // [sec][m][i]
    __shared__ float  sLpj[204];          // [sec][j]
    __shared__ float  xe_s[1734];         // one node's xe row (867 float2)
    __shared__ float  lpe_s[867];         // one node's lpe row

    {
        const float2* tc = (const float2*)TABC.v;
        tab[tid] = tc[tid];
        if (tid < 33) tab[256 + tid] = tc[256 + tid];
    }

    const size_t cbase = (size_t)cb * NNODE;

    if (tid < 48) {
        int nn = tid / 12, r = tid - nn * 12;
        int n = n0 + nn;
        size_t b1a = (cbase + n) * 3;
        size_t b2a = (cbase + (size_t)idOf(n)) * 3;
        float v;
        if (r < 3)      v = mu[b1a + r];
        else if (r < 6) v = sg[b1a + r - 3];
        else if (r < 9) v = mu[b2a + r - 6];
        else            v = sg[b2a + r - 9];
        params[tid] = v;
    }

    // softmax alphas (uniform across block)
    const float* wB = w + cb * 3;
    float w0 = wB[0], w1 = wB[1], w2 = wB[2];
    float wm = fmaxf(w0, fmaxf(w1, w2));
    float e0 = __expf(w0 - wm), e1 = __expf(w1 - wm), e2 = __expf(w2 - wm);
    float ainv = 1.0f / (e0 + e1 + e2);
    float a0 = e0 * ainv, a1 = e1 * ainv, a2 = e2 * ainv;

    __syncthreads();

    // ---- xn + lpn: threads 0..203 handle (nn, l1, k) = t/51, (t%51)/17, t%17 ----
    if (tid < 204) {
        int nn = tid / 51;
        int r  = tid - 51 * nn;
        int l1 = r / 17;
        int k  = r - 17 * l1;
        int n  = n0 + nn;
        size_t mb = (cbase + n) * 3;
        float ul = mu[mb + l1], sl = sg[mb + l1];
        float xn = fmaf(tab[k].x, sl, ul);      // tab[k].x = node_k * sqrt2
        out[OFF_XN + (cbase + n0) * 51 + tid] = xn;

        float lp = 0.0f;
        if (!(b >= 1 && n < 729)) {
            float ua = mu[mb], ub = mu[mb + 1], uc = mu[mb + 2];
            float ia = C_SCF * rcpf(sg[mb]);
            float ib = C_SCF * rcpf(sg[mb + 1]);
            float ic = C_SCF * rcpf(sg[mb + 2]);
            float d0 = (xn - ua) * ia;
            float d1 = (xn - ub) * ib;
            float d2 = (xn - uc) * ic;
            float sum = a0 * ia * exp2f(-(d0 * d0))
                      + a1 * ib * exp2f(-(d1 * d1))
                      + a2 * ic * exp2f(-(d2 * d2));
            lp = __logf(sum * KLPN + EPSF);
        }
        out[OFF_LPN + (cbase + n0) * 51 + tid] = lp;
    } else if (tid < 216) {           // o1: 4 nodes x 3
        int t = tid - 204; int nn = t / 3, c = t - 3 * nn; int n = n0 + nn;
        if (n < 819) out[OFF_O1 + ((size_t)cb * 819 + n) * 3 + c] = sg[(cbase + n) * 3 + c];
    } else if (tid < 228) {           // o2: 4 nodes x 3 (gathered)
        int t = tid - 216; int nn = t / 3, c = t - 3 * nn; int n = n0 + nn;
        if (n < 819) out[OFF_O2 + ((size_t)cb * 819 + n) * 3 + c] = sg[(cbase + idOf(n)) * 3 + c];
    }

    // ---- alpha (block (0,0), threads 0..53 as extra work) ----
    if (g == 0 && cb == 0 && tid < 54) {
        int cb2 = tid / 3, l = tid - 3 * cb2;
        const float* wB2 = w + cb2 * 3;
        float v0 = wB2[0], v1 = wB2[1], v2 = wB2[2];
        float vm = fmaxf(v0, fmaxf(v1, v2));
        float f0 = __expf(v0 - vm), f1 = __expf(v1 - vm), f2 = __expf(v2 - vm);
        float finv = 1.0f / (f0 + f1 + f2);
        float fl = (l == 0) ? f0 : ((l == 1) ? f1 : f2);
        out[OFF_ALPHA + tid] = fl * finv;
    }

    // ---- phase A: per-section factor tables ----
    for (int v = tid; v < 612; v += 256) {
        int s  = v / 51, r = v - s * 51;
        int m  = r / 17, j = r - m * 17;
        int nn = s / 3,  l1 = s - nn * 3;
        int n  = n0 + nn;
        const float* P = params + nn * 12;
        float u1l = P[l1],     s1l = P[3 + l1];
        float u2l = P[6 + l1], s2l = P[9 + l1];
        float u1m = P[m],      s1m = P[3 + m];
        float u2m = P[6 + m],  s2m = P[9 + m];
        float i2m = C_SCF * rcpf(s2m);
        float i1m = C_SCF * rcpf(s1m);
        float am  = sel3(a0, a1, a2, m);
        bool  mk  = (b >= 1) && (n < 729);
        float cm  = mk ? (am * i2m * KLPN) : (am * i1m * i2m * KE);
        float xv  = tab[j].x;                // node_j * sqrt2
        float x2j = fmaf(xv, s2l, u2l);
        float d   = (x2j - u2m) * i2m;
        sCEj[v] = cm * exp2f(-(d * d));
        float x1i = fmaf(xv, s1l, u1l);
        float f   = (x1i - u1m) * i1m;
        sEi[v]  = exp2f(-(f * f));
    }
    __syncthreads();
    if (tid < 204) {
        int s = tid / 17, j = tid - s * 17;
        float sum = sCEj[s * 51 + j] + sCEj[s * 51 + 17 + j] + sCEj[s * 51 + 34 + j];
        sLpj[tid] = __logf(sum + EPSF);
    }
    __syncthreads();

    // ---- streaming: xe + lpe via LDS staging + aligned dwordx4 write-out ----
    const int wv = tid >> 6, ln = tid & 63;
    const int j0 = tid / 17, i0 = tid - 17 * j0;
    const int qt = 256 + ln;
    const int jt = qt / 17, it = qt - 17 * jt;
    const size_t ecb = (size_t)cb * 819;

    for (int nn = 0; nn < G; ++nn) {
        int n = n0 + nn;
        if (n >= 819) break;             // uniform across block (only g=204,nn=3)
        const bool mk = (b >= 1) && (n < 729);
        const float* P = params + nn * 12;

#pragma unroll
        for (int l1 = 0; l1 < 3; ++l1) {
            const int sec = nn * 3 + l1;
            float u1l = P[l1],     s1l = P[3 + l1];
            float u2l = P[6 + l1], s2l = P[9 + l1];
            const float* CE = sCEj + sec * 51;
            const float* EI = sEi  + sec * 51;
            const float* LJ = sLpj + sec * 17;

            auto body = [&](int q, int i, int j) {
                float2 tv = tab[q];
                float x1 = fmaf(tv.x, s1l, u1l);
                float x2 = fmaf(tv.y, s2l, u2l);
                int qn = l1 * 289 + q;
                *(float2*)&xe_s[2 * qn] = make_float2(x1, x2);
                float lv;
                if (mk) {
                    lv = LJ[j];
                } else {
                    float sum = fmaf(EI[i], CE[j],
                                fmaf(EI[17 + i], CE[17 + j],
                                     EI[34 + i] * CE[34 + j]));
                    lv = __logf(sum + EPSF);
                }
                lpe_s[qn] = lv;
            };

            body(tid, i0, j0);                                // q in [0,256)
            if (wv == (sec & 3) && ln < 33) body(qt, it, jt); // q in [256,289)
        }
        __syncthreads();
        store_aligned(out + OFF_XE  + (ecb + n) * 1734, xe_s,  1734, tid);
        store_aligned(out + OFF_LPE + (ecb + n) * 867,  lpe_s, 867,  tid);
        __syncthreads();
    }
}

extern "C" void kernel_launch(void* const* d_in, const int* in_sizes, int n_in,
                              void* d_out, int out_size, void* d_ws, size_t ws_size,
                              hipStream_t stream) {
    const float* mu    = (const float*)d_in[0];
    const float* sigma = (const float*)d_in[1];
    const float* w     = (const float*)d_in[2];
    float* out = (float*)d_out;

    hipLaunchKernelGGL(fused_kernel, dim3(NGB, NC * NB), dim3(256), 0, stream,
                       mu, sigma, w, out);
}

// Round 9
// 35.160 us; speedup vs baseline: 1.0309x; 1.0309x over previous
//
#include <hip/hip_runtime.h>

// ---------------- problem constants ----------------
#define NC    2
#define NB    9
#define NNODE 820
#define NL    3
#define NK    17
#define G     8          // nodes per block
#define NGB   103        // ceil(820 / G)

#define EPSF     1e-30f
// scale constant: C = sqrt(log2(e)/2); exp(-d^2/2) == exp2(-(d*C)^2)
#define C_SCF    0.84932178f
// ISQ2PI / C   (pdf normalization when one 1/sigma factor is C-scaled)
#define KLPN     0.46971920f
// I2PI / C^2   (normalization when two 1/sigma factors are C-scaled)
#define KE       0.22063560f

// output layout (flat f32 offsets, concatenated in reference return order)
#define OFF_XN    0LL
#define OFF_XE    752760LL
#define OFF_LPN   26315388LL
#define OFF_LPE   27068148LL
#define OFF_ALPHA 39849462LL
#define OFF_O1    39849516LL
#define OFF_O2    39893742LL

// ---------------- compile-time Gauss-Hermite nodes (n=17) ----------------
constexpr double csqrt(double v) {
    if (v <= 0.0) return 0.0;
    double y = v > 1.0 ? v : 1.0;
    for (int i = 0; i < 80; ++i) y = 0.5 * (y + v / y);
    return y;
}

struct HNodesF { float x[NK]; };

constexpr HNodesF compute_nodes() {
    const int n = NK;
    const double PIM4 = 0.7511255444649425;   // pi^{-1/4}
    double c1[NK + 1] = {}, c2[NK + 1] = {};
    for (int j = 1; j <= n; ++j) {
        c1[j] = csqrt(2.0 / (double)j);
        c2[j] = csqrt(((double)j - 1.0) / (double)j);
    }
    const double PPC = csqrt(2.0 * (double)n);
    double xr[9] = {};
    double z = 0.0;
    for (int i = 0; i < 9; ++i) {
        if (i == 0)      z = csqrt(2.0 * n + 1.0) - 1.85575 * 0.552905;   // 35^-0.16667
        else if (i == 1) z -= 1.14 * 3.34327 / z;                          // 17^0.426
        else if (i == 2) z = 1.86 * z - 0.86 * xr[0];
        else if (i == 3) z = 1.91 * z - 0.91 * xr[1];
        else             z = 2.0 * z - xr[i - 2];
        for (int it = 0; it < 24; ++it) {
            double p1 = PIM4, p2 = 0.0;
            for (int j = 1; j <= n; ++j) {
                double p3 = p2;
                p2 = p1;
                p1 = z * c1[j] * p2 - c2[j] * p3;
            }
            double pp = PPC * p2;
            double z1 = z;
            z = z1 - p1 / pp;
            double d = z - z1; if (d < 0.0) d = -d;
            if (d <= 3.0e-14) break;
        }
        xr[i] = z;
    }
    HNodesF f{};
    for (int i = 0; i < 9; ++i) {
        f.x[16 - i] = (float)xr[i];
        f.x[i]      = (float)(-xr[i]);
    }
    return f;
}

// (xi*sqrt2, xj*sqrt2) table for q in [0,289): xi = x[q%17], xj = x[q/17]
struct TabF { float v[289 * 2]; };
constexpr TabF make_tab() {
    HNodesF h = compute_nodes();
    TabF t{};
    for (int q = 0; q < 289; ++q) {
        t.v[2 * q]     = (float)((double)h.x[q % 17] * 1.4142135623730951);
        t.v[2 * q + 1] = (float)((double)h.x[q / 17] * 1.4142135623730951);
    }
    return t;
}
constexpr TabF TABC = make_tab();

__device__ __forceinline__ int idOf(int n) {
    if (n < 729) { return 729 + (n / 81) * 9 + (n % 27) / 3; }
    if (n < 810) { int m = n - 729; return 810 + (m / 27) * 3 + (m % 9) / 3; }
    return 819;
}

__device__ __forceinline__ float rcpf(float x) { return __builtin_amdgcn_rcpf(x); }

__device__ __forceinline__ float sel3(float a0, float a1, float a2, int i) {
    float r = a0;
    r = (i == 1) ? a1 : r;
    r = (i == 2) ? a2 : r;
    return r;
}

// ---------------- single fused kernel ----------------
// grid = (103, 18); block (g, cb) handles 8 nodes n0..n0+7 of batch-slice cb.
// G=8 (vs 4): halves block count (1854, ~7.2/CU -> single residency round),
// halves wave-launch ramp and per-block preamble instances. Phase order:
// preamble -> factor tables -> BULK STREAM (xe/lpe) -> small scattered
// writes (xn/lpn/o1/o2/alpha) in the drain shadow, served from params LDS.
__global__ __launch_bounds__(256) void fused_kernel(const float* __restrict__ mu,
                                                    const float* __restrict__ sg,
                                                    const float* __restrict__ w,
                                                    float* __restrict__ out) {
    const int g   = blockIdx.x;           // 0..102
    const int cb  = blockIdx.y;           // 0..17
    const int b   = cb % NB;
    const int n0  = g * G;
    const int tid = threadIdx.x;

    __shared__ float2 tab[289];
    __shared__ float  params[96];         // [nn][12]: mu1[3],sg1[3],mu2[3],sg2[3]
    __shared__ float  sCEj[1224];         // [sec][m][j]  sec=nn*3+l1, 24 sections
    __shared__ float  sEi [1224];         // [sec][m][i]
    __shared__ float  sLpj[408];          // [sec][j]

    {
        const float2* tc = (const float2*)TABC.v;
        tab[tid] = tc[tid];
        if (tid < 33) tab[256 + tid] = tc[256 + tid];
    }

    const size_t cbase = (size_t)cb * NNODE;

    if (tid < 96) {
        int nn = tid / 12, r = tid - nn * 12;
        int n = n0 + nn;
        if (n > 819) n = 819;             // clamp: g=102,nn>=4 values unused
        size_t b1a = (cbase + n) * 3;
        size_t b2a = (cbase + (size_t)idOf(n)) * 3;
        float v;
        if (r < 3)      v = mu[b1a + r];
        else if (r < 6) v = sg[b1a + r - 3];
        else if (r < 9) v = mu[b2a + r - 6];
        else            v = sg[b2a + r - 9];
        params[tid] = v;
    }

    // softmax alphas (uniform across block)
    const float* wB = w + cb * 3;
    float w0 = wB[0], w1 = wB[1], w2 = wB[2];
    float wm = fmaxf(w0, fmaxf(w1, w2));
    float e0 = __expf(w0 - wm), e1 = __expf(w1 - wm), e2 = __expf(w2 - wm);
    float ainv = 1.0f / (e0 + e1 + e2);
    float a0 = e0 * ainv, a1 = e1 * ainv, a2 = e2 * ainv;

    __syncthreads();

    // ---- phase A: per-section factor tables (24 sections x 3 m x 17 j) ----
    for (int v = tid; v < 1224; v += 256) {
        int s  = v / 51, r = v - s * 51;
        int m  = r / 17, j = r - m * 17;
        int nn = s / 3,  l1 = s - nn * 3;
        int n  = n0 + nn;
        const float* P = params + nn * 12;
        float u1l = P[l1],     s1l = P[3 + l1];
        float u2l = P[6 + l1], s2l = P[9 + l1];
        float u1m = P[m],      s1m = P[3 + m];
        float u2m = P[6 + m],  s2m = P[9 + m];
        float i2m = C_SCF * rcpf(s2m);
        float i1m = C_SCF * rcpf(s1m);
        float am  = sel3(a0, a1, a2, m);
        bool  mk  = (b >= 1) && (n < 729);
        float cm  = mk ? (am * i2m * KLPN) : (am * i1m * i2m * KE);
        float xv  = tab[j].x;                // node_j * sqrt2
        float x2j = fmaf(xv, s2l, u2l);
        float d   = (x2j - u2m) * i2m;
        sCEj[v] = cm * exp2f(-(d * d));
        float x1i = fmaf(xv, s1l, u1l);
        float f   = (x1i - u1m) * i1m;
        sEi[v]  = exp2f(-(f * f));
    }
    __syncthreads();
    for (int t = tid; t < 408; t += 256) {
        int s = t / 17, j = t - s * 17;
        float sum = sCEj[s * 51 + j] + sCEj[s * 51 + 17 + j] + sCEj[s * 51 + 34 + j];
        sLpj[t] = __logf(sum + EPSF);
    }
    __syncthreads();

    // ---- bulk stream: xe + lpe ----
    const int wv = tid >> 6, ln = tid & 63;
    const int j0 = tid / 17, i0 = tid - 17 * j0;
    const int qt = 256 + ln;
    const int jt = qt / 17, it = qt - 17 * jt;
    const size_t ecb = (size_t)cb * 819;

    for (int nn = 0; nn < G; ++nn) {
        int n = n0 + nn;
        if (n >= 819) break;             // uniform across block
        const bool mk = (b >= 1) && (n < 729);
        const float* P = params + nn * 12;
        float2* xp0 = reinterpret_cast<float2*>(out + OFF_XE) + (ecb + n) * 867;
        float*  lp0 = out + OFF_LPE + (ecb + n) * 867;

#pragma unroll
        for (int l1 = 0; l1 < 3; ++l1) {
            const int sec = nn * 3 + l1;
            float u1l = P[l1],     s1l = P[3 + l1];
            float u2l = P[6 + l1], s2l = P[9 + l1];
            float2* xp = xp0 + l1 * 289;
            float*  lp = lp0 + l1 * 289;
            const float* CE = sCEj + sec * 51;
            const float* EI = sEi  + sec * 51;
            const float* LJ = sLpj + sec * 17;

            auto body = [&](int q, int i, int j) {
                float2 tv = tab[q];
                float x1 = fmaf(tv.x, s1l, u1l);
                float x2 = fmaf(tv.y, s2l, u2l);
                xp[q] = make_float2(x1, x2);
                float lv;
                if (mk) {
                    lv = LJ[j];
                } else {
                    float sum = fmaf(EI[i], CE[j],
                                fmaf(EI[17 + i], CE[17 + j],
                                     EI[34 + i] * CE[34 + j]));
                    lv = __logf(sum + EPSF);
                }
                lp[q] = lv;
            };

            body(tid, i0, j0);                                // q in [0,256)
            if (wv == (sec & 3) && ln < 33) body(qt, it, jt); // q in [256,289)
        }
    }

    // ---- small scattered outputs (drain shadow): xn, lpn, o1, o2, alpha ----
    for (int t = tid; t < G * 51; t += 256) {
        int nn = t / 51;
        int n  = n0 + nn;
        if (n >= 820) break;              // t monotone per thread -> safe
        int r  = t - 51 * nn;
        int l1 = r / 17;
        int k  = r - 17 * l1;
        const float* P = params + nn * 12;
        float ul = P[l1], sl = P[3 + l1];
        float xn = fmaf(tab[k].x, sl, ul);
        out[OFF_XN + (cbase + n0) * 51 + t] = xn;

        float lp = 0.0f;
        if (!(b >= 1 && n < 729)) {
            float ia = C_SCF * rcpf(P[3]);
            float ib = C_SCF * rcpf(P[4]);
            float ic = C_SCF * rcpf(P[5]);
            float d0 = (xn - P[0]) * ia;
            float d1 = (xn - P[1]) * ib;
            float d2 = (xn - P[2]) * ic;
            float sum = a0 * ia * exp2f(-(d0 * d0))
                      + a1 * ib * exp2f(-(d1 * d1))
                      + a2 * ic * exp2f(-(d2 * d2));
            lp = __logf(sum * KLPN + EPSF);
        }
        out[OFF_LPN + (cbase + n0) * 51 + t] = lp;
    }

    if (tid < 24) {                       // o1: 8 nodes x 3
        int nn = tid / 3, c = tid - 3 * nn;
        int n = n0 + nn;
        if (n < 819) out[OFF_O1 + (ecb + n) * 3 + c] = params[nn * 12 + 3 + c];
    } else if (tid < 48) {                // o2: 8 nodes x 3 (gathered sigma)
        int t = tid - 24;
        int nn = t / 3, c = t - 3 * nn;
        int n = n0 + nn;
        if (n < 819) out[OFF_O2 + (ecb + n) * 3 + c] = params[nn * 12 + 9 + c];
    }

    if (g == 0 && cb == 0 && tid >= 64 && tid < 118) {   // alpha (54)
        int t = tid - 64;
        int cb2 = t / 3, l = t - 3 * cb2;
        const float* wB2 = w + cb2 * 3;
        float v0 = wB2[0], v1 = wB2[1], v2 = wB2[2];
        float vm = fmaxf(v0, fmaxf(v1, v2));
        float f0 = __expf(v0 - vm), f1 = __expf(v1 - vm), f2 = __expf(v2 - vm);
        float finv = 1.0f / (f0 + f1 + f2);
        float fl = (l == 0) ? f0 : ((l == 1) ? f1 : f2);
        out[OFF_ALPHA + t] = fl * finv;
    }
}

extern "C" void kernel_launch(void* const* d_in, const int* in_sizes, int n_in,
                              void* d_out, int out_size, void* d_ws, size_t ws_size,
                              hipStream_t stream) {
    const float* mu    = (const float*)d_in[0];
    const float* sigma = (const float*)d_in[1];
    const float* w     = (const float*)d_in[2];
    float* out = (float*)d_out;

    hipLaunchKernelGGL(fused_kernel, dim3(NGB, NC * NB), dim3(256), 0, stream,
                       mu, sigma, w, out);
}

// Round 10
// 34.353 us; speedup vs baseline: 1.0552x; 1.0235x over previous
//
#include <hip/hip_runtime.h>

// ---------------- problem constants ----------------
#define NC    2
#define NB    9
#define NNODE 820
#define NL    3
#define NK    17
#define GA    4          // nodes per role-A (xe) block
#define NGA   205        // 820 / GA
#define GB    8          // nodes per role-B (lpe+misc) block
#define NGBB  103        // ceil(820 / GB)

#define EPSF     1e-30f
// scale constant: C = sqrt(log2(e)/2); exp(-d^2/2) == exp2(-(d*C)^2)
#define C_SCF    0.84932178f
// ISQ2PI / C   (pdf normalization when one 1/sigma factor is C-scaled)
#define KLPN     0.46971920f
// I2PI / C^2   (normalization when two 1/sigma factors are C-scaled)
#define KE       0.22063560f

// output layout (flat f32 offsets, concatenated in reference return order)
#define OFF_XN    0LL
#define OFF_XE    752760LL
#define OFF_LPN   26315388LL
#define OFF_LPE   27068148LL
#define OFF_ALPHA 39849462LL
#define OFF_O1    39849516LL
#define OFF_O2    39893742LL

// ---------------- compile-time Gauss-Hermite nodes (n=17) ----------------
constexpr double csqrt(double v) {
    if (v <= 0.0) return 0.0;
    double y = v > 1.0 ? v : 1.0;
    for (int i = 0; i < 80; ++i) y = 0.5 * (y + v / y);
    return y;
}

struct HNodesF { float x[NK]; };

constexpr HNodesF compute_nodes() {
    const int n = NK;
    const double PIM4 = 0.7511255444649425;   // pi^{-1/4}
    double c1[NK + 1] = {}, c2[NK + 1] = {};
    for (int j = 1; j <= n; ++j) {
        c1[j] = csqrt(2.0 / (double)j);
        c2[j] = csqrt(((double)j - 1.0) / (double)j);
    }
    const double PPC = csqrt(2.0 * (double)n);
    double xr[9] = {};
    double z = 0.0;
    for (int i = 0; i < 9; ++i) {
        if (i == 0)      z = csqrt(2.0 * n + 1.0) - 1.85575 * 0.552905;   // 35^-0.16667
        else if (i == 1) z -= 1.14 * 3.34327 / z;                          // 17^0.426
        else if (i == 2) z = 1.86 * z - 0.86 * xr[0];
        else if (i == 3) z = 1.91 * z - 0.91 * xr[1];
        else             z = 2.0 * z - xr[i - 2];
        for (int it = 0; it < 24; ++it) {
            double p1 = PIM4, p2 = 0.0;
            for (int j = 1; j <= n; ++j) {
                double p3 = p2;
                p2 = p1;
                p1 = z * c1[j] * p2 - c2[j] * p3;
            }
            double pp = PPC * p2;
            double z1 = z;
            z = z1 - p1 / pp;
            double d = z - z1; if (d < 0.0) d = -d;
            if (d <= 3.0e-14) break;
        }
        xr[i] = z;
    }
    HNodesF f{};
    for (int i = 0; i < 9; ++i) {
        f.x[16 - i] = (float)xr[i];
        f.x[i]      = (float)(-xr[i]);
    }
    return f;
}

// (xi*sqrt2, xj*sqrt2) table for q in [0,289): xi = x[q%17], xj = x[q/17]
struct TabF { float v[289 * 2]; };
constexpr TabF make_tab() {
    HNodesF h = compute_nodes();
    TabF t{};
    for (int q = 0; q < 289; ++q) {
        t.v[2 * q]     = (float)((double)h.x[q % 17] * 1.4142135623730951);
        t.v[2 * q + 1] = (float)((double)h.x[q / 17] * 1.4142135623730951);
    }
    return t;
}
constexpr TabF TABC = make_tab();

__device__ __forceinline__ int idOf(int n) {
    if (n < 729) { return 729 + (n / 81) * 9 + (n % 27) / 3; }
    if (n < 810) { int m = n - 729; return 810 + (m / 27) * 3 + (m % 9) / 3; }
    return 819;
}

__device__ __forceinline__ float rcpf(float x) { return __builtin_amdgcn_rcpf(x); }

__device__ __forceinline__ float sel3(float a0, float a1, float a2, int i) {
    float r = a0;
    r = (i == 1) ? a1 : r;
    r = (i == 2) ? a2 : r;
    return r;
}

// ---------------- single fused kernel, region-specialized blocks ----------------
// grid = (205 + 103, 18). Blocks gx<205 are role A (xe only, 4 nodes each):
// each wave issues ONE pure contiguous write stream. Blocks gx>=205 are
// role B (lpe via factor tables, 8 nodes each, plus xn/lpn/o1/o2/alpha).
// Tests whether per-wave interleave of two far-apart store streams was
// capping effective HBM write BW (~4.8 vs 6.5 TB/s fill).
__global__ __launch_bounds__(256) void fused_kernel(const float* __restrict__ mu,
                                                    const float* __restrict__ sg,
                                                    const float* __restrict__ w,
                                                    float* __restrict__ out) {
    const int gx  = blockIdx.x;
    const int cb  = blockIdx.y;           // 0..17
    const int b   = cb % NB;
    const int tid = threadIdx.x;
    const size_t cbase = (size_t)cb * NNODE;
    const size_t ecb   = (size_t)cb * 819;
    const int wv = tid >> 6, ln = tid & 63;

    __shared__ float2 tab[289];
    __shared__ float  params[96];         // [nn][12]: mu1[3],sg1[3],mu2[3],sg2[3]
    __shared__ float  sCEj[1224];         // [sec][m][j]  sec=nn*3+l1 (role B)
    __shared__ float  sEi [1224];         // [sec][m][i]
    __shared__ float  sLpj[408];          // [sec][j]

    {
        const float2* tc = (const float2*)TABC.v;
        tab[tid] = tc[tid];
        if (tid < 33) tab[256 + tid] = tc[256 + tid];
    }

    if (gx < NGA) {
        // ================= role A: xe stream only =================
        const int n0 = gx * GA;
        if (tid < GA * 12) {
            int nn = tid / 12, r = tid - nn * 12;
            int n = n0 + nn;
            size_t b1a = (cbase + n) * 3;
            size_t b2a = (cbase + (size_t)idOf(n)) * 3;
            float v;
            if (r < 3)      v = mu[b1a + r];
            else if (r < 6) v = sg[b1a + r - 3];
            else if (r < 9) v = mu[b2a + r - 6];
            else            v = sg[b2a + r - 9];
            params[tid] = v;
        }
        __syncthreads();

        for (int nn = 0; nn < GA; ++nn) {
            int n = n0 + nn;
            if (n >= 819) break;
            const float* P = params + nn * 12;
            float2* xp0 = reinterpret_cast<float2*>(out + OFF_XE) + (ecb + n) * 867;
#pragma unroll
            for (int l1 = 0; l1 < 3; ++l1) {
                float u1l = P[l1],     s1l = P[3 + l1];
                float u2l = P[6 + l1], s2l = P[9 + l1];
                float2* xp = xp0 + l1 * 289;
                {
                    float2 tv = tab[tid];
                    xp[tid] = make_float2(fmaf(tv.x, s1l, u1l), fmaf(tv.y, s2l, u2l));
                }
                const int sec = nn * 3 + l1;
                if (wv == (sec & 3) && ln < 33) {
                    int q = 256 + ln;
                    float2 tv = tab[q];
                    xp[q] = make_float2(fmaf(tv.x, s1l, u1l), fmaf(tv.y, s2l, u2l));
                }
            }
        }
        return;
    }

    // ================= role B: lpe + xn/lpn + o1/o2 + alpha =================
    const int gb = gx - NGA;
    const int n0 = gb * GB;

    if (tid < GB * 12) {
        int nn = tid / 12, r = tid - nn * 12;
        int n = n0 + nn;
        if (n > 819) n = 819;             // clamp: gb=102,nn>=4 values unused
        size_t b1a = (cbase + n) * 3;
        size_t b2a = (cbase + (size_t)idOf(n)) * 3;
        float v;
        if (r < 3)      v = mu[b1a + r];
        else if (r < 6) v = sg[b1a + r - 3];
        else if (r < 9) v = mu[b2a + r - 6];
        else            v = sg[b2a + r - 9];
        params[tid] = v;
    }

    // softmax alphas (uniform across block)
    const float* wB = w + cb * 3;
    float w0 = wB[0], w1 = wB[1], w2 = wB[2];
    float wm = fmaxf(w0, fmaxf(w1, w2));
    float e0 = __expf(w0 - wm), e1 = __expf(w1 - wm), e2 = __expf(w2 - wm);
    float ainv = 1.0f / (e0 + e1 + e2);
    float a0 = e0 * ainv, a1 = e1 * ainv, a2 = e2 * ainv;

    __syncthreads();

    // ---- phase A: per-section factor tables (24 sections x 3 m x 17 j) ----
    for (int v = tid; v < 1224; v += 256) {
        int s  = v / 51, r = v - s * 51;
        int m  = r / 17, j = r - m * 17;
        int nn = s / 3,  l1 = s - nn * 3;
        int n  = n0 + nn;
        const float* P = params + nn * 12;
        float u1l = P[l1],     s1l = P[3 + l1];
        float u2l = P[6 + l1], s2l = P[9 + l1];
        float u1m = P[m],      s1m = P[3 + m];
        float u2m = P[6 + m],  s2m = P[9 + m];
        float i2m = C_SCF * rcpf(s2m);
        float i1m = C_SCF * rcpf(s1m);
        float am  = sel3(a0, a1, a2, m);
        bool  mk  = (b >= 1) && (n < 729);
        float cm  = mk ? (am * i2m * KLPN) : (am * i1m * i2m * KE);
        float xv  = tab[j].x;                // node_j * sqrt2
        float x2j = fmaf(xv, s2l, u2l);
        float d   = (x2j - u2m) * i2m;
        sCEj[v] = cm * exp2f(-(d * d));
        float x1i = fmaf(xv, s1l, u1l);
        float f   = (x1i - u1m) * i1m;
        sEi[v]  = exp2f(-(f * f));
    }
    __syncthreads();
    for (int t = tid; t < 408; t += 256) {
        int s = t / 17, j = t - s * 17;
        float sum = sCEj[s * 51 + j] + sCEj[s * 51 + 17 + j] + sCEj[s * 51 + 34 + j];
        sLpj[t] = __logf(sum + EPSF);
    }
    __syncthreads();

    // ---- bulk stream: lpe only ----
    const int j0 = tid / 17, i0 = tid - 17 * j0;
    const int qt = 256 + ln;
    const int jt = qt / 17, it = qt - 17 * jt;

    for (int nn = 0; nn < GB; ++nn) {
        int n = n0 + nn;
        if (n >= 819) break;
        const bool mk = (b >= 1) && (n < 729);
        float* lp0 = out + OFF_LPE + (ecb + n) * 867;

#pragma unroll
        for (int l1 = 0; l1 < 3; ++l1) {
            const int sec = nn * 3 + l1;
            float* lp = lp0 + l1 * 289;
            const float* CE = sCEj + sec * 51;
            const float* EI = sEi  + sec * 51;
            const float* LJ = sLpj + sec * 17;

            auto body = [&](int q, int i, int j) {
                float lv;
                if (mk) {
                    lv = LJ[j];
                } else {
                    float sum = fmaf(EI[i], CE[j],
                                fmaf(EI[17 + i], CE[17 + j],
                                     EI[34 + i] * CE[34 + j]));
                    lv = __logf(sum + EPSF);
                }
                lp[q] = lv;
            };

            body(tid, i0, j0);                                // q in [0,256)
            if (wv == (sec & 3) && ln < 33) body(qt, it, jt); // q in [256,289)
        }
    }

    // ---- small scattered outputs: xn, lpn ----
    for (int t = tid; t < GB * 51; t += 256) {
        int nn = t / 51;
        int n  = n0 + nn;
        if (n >= 820) break;              // t monotone per thread -> safe
        int r  = t - 51 * nn;
        int l1 = r / 17;
        int k  = r - 17 * l1;
        const float* P = params + nn * 12;
        float ul = P[l1], sl = P[3 + l1];
        float xn = fmaf(tab[k].x, sl, ul);
        out[OFF_XN + (cbase + n0) * 51 + t] = xn;

        float lp = 0.0f;
        if (!(b >= 1 && n < 729)) {
            float ia = C_SCF * rcpf(P[3]);
            float ib = C_SCF * rcpf(P[4]);
            float ic = C_SCF * rcpf(P[5]);
            float d0 = (xn - P[0]) * ia;
            float d1 = (xn - P[1]) * ib;
            float d2 = (xn - P[2]) * ic;
            float sum = a0 * ia * exp2f(-(d0 * d0))
                      + a1 * ib * exp2f(-(d1 * d1))
                      + a2 * ic * exp2f(-(d2 * d2));
            lp = __logf(sum * KLPN + EPSF);
        }
        out[OFF_LPN + (cbase + n0) * 51 + t] = lp;
    }

    if (tid < 24) {                       // o1: 8 nodes x 3
        int nn = tid / 3, c = tid - 3 * nn;
        int n = n0 + nn;
        if (n < 819) out[OFF_O1 + (ecb + n) * 3 + c] = params[nn * 12 + 3 + c];
    } else if (tid < 48) {                // o2: 8 nodes x 3 (gathered sigma)
        int t = tid - 24;
        int nn = t / 3, c = t - 3 * nn;
        int n = n0 + nn;
        if (n < 819) out[OFF_O2 + (ecb + n) * 3 + c] = params[nn * 12 + 9 + c];
    }

    if (gb == 0 && cb == 0 && tid >= 64 && tid < 118) {   // alpha (54)
        int t = tid - 64;
        int cb2 = t / 3, l = t - 3 * cb2;
        const float* wB2 = w + cb2 * 3;
        float v0 = wB2[0], v1 = wB2[1], v2 = wB2[2];
        float vm = fmaxf(v0, fmaxf(v1, v2));
        float f0 = __expf(v0 - vm), f1 = __expf(v1 - vm), f2 = __expf(v2 - vm);
        float finv = 1.0f / (f0 + f1 + f2);
        float fl = (l == 0) ? f0 : ((l == 1) ? f1 : f2);
        out[OFF_ALPHA + t] = fl * finv;
    }
}

extern "C" void kernel_launch(void* const* d_in, const int* in_sizes, int n_in,
                              void* d_out, int out_size, void* d_ws, size_t ws_size,
                              hipStream_t stream) {
    const float* mu    = (const float*)d_in[0];
    const float* sigma = (const float*)d_in[1];
    const float* w     = (const float*)d_in[2];
    float* out = (float*)d_out;

    hipLaunchKernelGGL(fused_kernel, dim3(NGA + NGBB, NC * NB), dim3(256), 0, stream,
                       mu, sigma, w, out);
}